// Round 16
// baseline (242.478 us; speedup 1.0000x reference)
//
#include <hip/hip_runtime.h>
#include <hip/hip_bf16.h>
#include <math.h>

typedef short s16x8 __attribute__((ext_vector_type(8)));
typedef float f32x4 __attribute__((ext_vector_type(4)));

__device__ inline ushort f2bf(float f) {
  unsigned u = __float_as_uint(f);
  u = (u + 0x7FFF + ((u >> 16) & 1)) >> 16;
  return (ushort)u;
}
__device__ inline float bf2f(ushort u) {
  return __uint_as_float(((unsigned)u) << 16);
}
// packed f32x2 -> bf16x2 RNE; v_cvt_pk_bf16_f32 on gfx950 (bit-identical to f2bf pair)
__device__ inline unsigned pkbf(float a, float b) {
  __hip_bfloat162 h = __float22bfloat162_rn(make_float2(a, b));
  return *(unsigned*)&h;
}
// fast activations: v_exp_f32 + v_rcp_f32; saturate correctly at +/-inf.
__device__ inline float fast_tanh(float v) {
  float e = __builtin_amdgcn_exp2f(v * 2.8853900817779268f);   // exp(2v)
  return 1.f - 2.f * __builtin_amdgcn_rcpf(e + 1.f);
}
__device__ inline float fast_sigmoid(float v) {
  float e = __builtin_amdgcn_exp2f(v * -1.4426950408889634f);  // exp(-v)
  return __builtin_amdgcn_rcpf(1.f + e);
}

// ---- PERMUTED head-row space (640 rows):
//   g in [0,18): off | [18,27): mod | [27,64): pad | [64,640): col j=g-64=k*64+c
//     source col channel cc = c*9+k.
// ---- K0: pack weights into MFMA-fragment order in permuted row space ------------------
// Wpk[og 5][ks 18][ocq 2][mi 4][lane 64][e 8]; W2pk[ks 18][mi 4][lane 64][e 8].
__global__ __launch_bounds__(256) void k_merge(
    const float* __restrict__ wp, const float* __restrict__ bp,
    const float* __restrict__ wm, const float* __restrict__ bm,
    const float* __restrict__ wc, const float* __restrict__ bc,
    const float* __restrict__ wconv,
    ushort* __restrict__ Wpk, float* __restrict__ Bc, ushort* __restrict__ W2pk) {
  int i = blockIdx.x * 256 + threadIdx.x;
  if (i < 368640) {
    int e = i & 7, lane = (i >> 3) & 63, mi = (i >> 9) & 3, ocq = (i >> 11) & 1;
    int hi = i >> 12;                 // 0..89
    int ks = hi % 18, og = hi / 18;
    int g = og * 128 + ocq * 64 + mi * 16 + (lane & 15);
    int ci = ((ks & 1) << 5) + ((lane >> 4) << 3) + e;
    int kk = ks >> 1;
    int col = ci * 9 + kk;
    float v = 0.f;
    if (g < 18)       v = wp[g * 576 + col];
    else if (g < 27)  v = wm[(g - 18) * 576 + col];
    else if (g >= 64) {
      int j = g - 64;
      int cc = (j & 63) * 9 + (j >> 6);
      v = wc[cc * 576 + col];
    }
    Wpk[i] = f2bf(v);
  }
  if (i < 36864) {
    int e = i & 7, lane = (i >> 3) & 63, mi = (i >> 9) & 3, ks = i >> 11;  // 0..17
    int o = mi * 16 + (lane & 15);
    int p = (ks << 5) + ((lane >> 4) << 3) + e;
    int kk2 = p >> 6, c = p & 63;
    W2pk[i] = f2bf(wconv[o * 576 + c * 9 + kk2]);
  }
  if (i < 640) {
    float bv = 0.f;
    if (i < 18)       bv = bp[i];
    else if (i < 27)  bv = bm[i - 18];
    else if (i >= 64) {
      int j = i - 64;
      bv = bc[(j & 63) * 9 + (j >> 6)];
    }
    Bc[i] = bv;
  }
}

// ---- K1: fused = 1x1 conv -> fusedt[pix][64] bf16. 4 thr/px x 16 oc, 16 waves/CU ------
__global__ __launch_bounds__(256) void k_fused(
    const float* __restrict__ x, const float* __restrict__ ref,
    const float* __restrict__ wcd, const float* __restrict__ bcd,
    ushort* __restrict__ fusedt) {
  __shared__ float sw[128 * 64];
  __shared__ float sb[64];
  for (int i = threadIdx.x; i < 128 * 64; i += 256) {
    int ci = i >> 6, o = i & 63;
    sw[i] = wcd[o * 128 + ci];
  }
  if (threadIdx.x < 64) sb[threadIdx.x] = bcd[threadIdx.x];
  __syncthreads();

  const int t = threadIdx.x;
  const int pxi = t & 63, oq = t >> 6;      // wave-uniform oq -> LDS broadcast
  const int pix = blockIdx.x * 64 + pxi;
  const int b = pix >> 14, hw = pix & 16383;
  const float* xb = x   + ((size_t)b * 64 << 14) + hw;
  const float* rb = ref + ((size_t)b * 64 << 14) + hw;

  float4 acc[4];
  #pragma unroll
  for (int q = 0; q < 4; q++)
    acc[q] = *(const float4*)&sb[oq * 16 + 4 * q];

  for (int ci = 0; ci < 64; ci++) {
    float v = xb[(size_t)ci << 14];
    const float4* wr = (const float4*)&sw[ci * 64 + oq * 16];
    #pragma unroll
    for (int q = 0; q < 4; q++) {
      float4 w4 = wr[q];
      acc[q].x += w4.x * v; acc[q].y += w4.y * v;
      acc[q].z += w4.z * v; acc[q].w += w4.w * v;
    }
  }
  for (int ci = 0; ci < 64; ci++) {
    float v = rb[(size_t)ci << 14];
    const float4* wr = (const float4*)&sw[(64 + ci) * 64 + oq * 16];
    #pragma unroll
    for (int q = 0; q < 4; q++) {
      float4 w4 = wr[q];
      acc[q].x += w4.x * v; acc[q].y += w4.y * v;
      acc[q].z += w4.z * v; acc[q].w += w4.w * v;
    }
  }
  uint4 o0, o1;
  o0.x = pkbf(acc[0].x, acc[0].y); o0.y = pkbf(acc[0].z, acc[0].w);
  o0.z = pkbf(acc[1].x, acc[1].y); o0.w = pkbf(acc[1].z, acc[1].w);
  o1.x = pkbf(acc[2].x, acc[2].y); o1.y = pkbf(acc[2].z, acc[2].w);
  o1.z = pkbf(acc[3].x, acc[3].y); o1.w = pkbf(acc[3].z, acc[3].w);
  ushort* fb = fusedt + ((size_t)pix << 6) + oq * 16;
  *(uint4*)fb       = o0;
  *(uint4*)(fb + 8) = o1;
}

// ---- K2: xtb[b][hw][c] bf16 pixel-major transpose of x -------------------------------
__global__ __launch_bounds__(256) void k_xt(
    const float* __restrict__ x, ushort* __restrict__ xtb) {
  __shared__ float sx[64][65];
  const int t = threadIdx.x;
  const int b = blockIdx.x >> 8, hw0 = (blockIdx.x & 255) << 6;
  for (int i = t; i < 4096; i += 256) {
    int c = i >> 6, hwi = i & 63;
    sx[c][hwi] = x[((size_t)(b * 64 + c) << 14) + hw0 + hwi];
  }
  __syncthreads();
  for (int i = t * 2; i < 4096; i += 512) {
    int hwi = i >> 6, c = i & 63;    // c even
    unsigned pk = pkbf(sx[c][hwi], sx[c + 1][hwi]);
    *(unsigned*)(xtb + (((size_t)b << 14) + hw0 + hwi) * 64 + c) = pk;
  }
}

// ---- K3: FULLY FUSED head-GEMM + sampler + final GEMM (R13 phase structure) -----------
// grid 512 (one 128-px image row per block); block 256 = 4 waves.
// Gathers issued in the sampler phase interleaved per-corner (R13 best measured form).
__global__ __launch_bounds__(256) void k_all(
    const ushort* __restrict__ Wpk, const ushort* __restrict__ fusedt,
    const float* __restrict__ Bc, const ushort* __restrict__ xtb,
    const ushort* __restrict__ W2pk, float* __restrict__ out) {
  __shared__ __align__(16) ushort sF[3 * 130 * 64];   // 49,920 B
  __shared__ __align__(16) ushort colT[128 * 64];     // 16,384 B
  __shared__ float homT[128 * 29];                    // 14,848 B
  const int t = threadIdx.x;
  const int lane = t & 63, wv = t >> 6;
  const int rowid = blockIdx.x;           // b*128 + h
  const int b = rowid >> 7, h = rowid & 127;
  const int hw0 = (rowid << 7) & 16383;

  // stage fused rows h-1..h+1
  for (int idx = t; idx < 3120; idx += 256) {
    int p = idx >> 3, j = idx & 7;
    int row = p / 130, w1 = p - row * 130;
    int gh = h + row - 1, gw = w1 - 1;
    uint4 v = make_uint4(0u, 0u, 0u, 0u);
    if (gh >= 0 && gh < 128 && (unsigned)gw < 128u)
      v = *(const uint4*)(fusedt + ((size_t)((b << 14) + (gh << 7) + gw) << 6) + j * 8);
    int slot = (j + w1) & 7;
    *(uint4*)(sF + (p << 6) + slot * 8) = v;
  }
  __syncthreads();

  const int pxq = wv & 1, rowq = wv >> 1;
  const int nif = lane & 15, kb = lane >> 4, quad = lane >> 4;

  // ---- off/mod GEMM: permuted rows 0..31 (rowq==0 waves only) ----
  if (rowq == 0) {
    f32x4 acc[2][4];
    #pragma unroll
    for (int mi = 0; mi < 2; mi++)
      #pragma unroll
      for (int ni = 0; ni < 4; ni++) acc[mi][ni] = (f32x4){0.f, 0.f, 0.f, 0.f};
    #pragma unroll 2
    for (int ks = 0; ks < 18; ks++) {
      const int kk = ks >> 1, half = ks & 1;
      const int dr = kk / 3, dc = kk - dr * 3;
      const ushort* wp8 = Wpk + ((size_t)(ks << 12)) + (lane << 3);  // og=0, ocq=0
      s16x8 af[2], bfr[4];
      #pragma unroll
      for (int mi = 0; mi < 2; mi++)
        af[mi] = *(const s16x8*)(wp8 + (mi << 9));
      const int gci = half * 4 + kb;
      #pragma unroll
      for (int ni = 0; ni < 4; ni++) {
        int r = (pxq << 6) + ni * 16 + nif;
        int w1 = r + dc;
        int slot = (gci + w1) & 7;
        bfr[ni] = *(const s16x8*)(sF + ((dr * 130 + w1) << 6) + slot * 8);
      }
      #pragma unroll
      for (int mi = 0; mi < 2; mi++)
        #pragma unroll
        for (int ni = 0; ni < 4; ni++)
          acc[mi][ni] = __builtin_amdgcn_mfma_f32_16x16x32_bf16(af[mi], bfr[ni], acc[mi][ni], 0, 0, 0);
    }
    #pragma unroll
    for (int mi = 0; mi < 2; mi++) {
      #pragma unroll
      for (int ni = 0; ni < 4; ni++) {
        int px = (pxq << 6) + ni * 16 + nif;
        #pragma unroll
        for (int r = 0; r < 4; r++) {
          int g = mi * 16 + (quad << 2) + r;
          float v = acc[mi][ni][r] + Bc[g];
          if (g < 18)       homT[px * 29 + g] = v;
          else if (g < 27)  homT[px * 29 + g] = fast_sigmoid(v);
        }
      }
    }
  }

  // sampler per-pixel identity
  const int chalf = t >> 7, pxl = t & 127, c0 = chalf << 5;
  const int hw = hw0 + pxl;
  const int ww = hw & 127;
  const ushort* xb = xtb + ((size_t)b << 20);

  f32x4 aco[2][4];
  #pragma unroll
  for (int mi = 0; mi < 2; mi++)
    #pragma unroll
    for (int ni = 0; ni < 4; ni++) aco[mi][ni] = (f32x4){0.f, 0.f, 0.f, 0.f};

  #pragma unroll 1
  for (int k = 0; k < 9; k++) {
    // ---- col GEMM for this k: permuted rows 64+k*64 .. 128+k*64 ----
    const int q = 1 + k, og = q >> 1, ocq = q & 1;
    f32x4 acc[2][4];
    #pragma unroll
    for (int mi = 0; mi < 2; mi++)
      #pragma unroll
      for (int ni = 0; ni < 4; ni++) acc[mi][ni] = (f32x4){0.f, 0.f, 0.f, 0.f};
    #pragma unroll 2
    for (int ks = 0; ks < 18; ks++) {
      const int kk = ks >> 1, half = ks & 1;
      const int dr = kk / 3, dc = kk - dr * 3;
      const ushort* wp8 = Wpk + ((size_t)((((og * 18 + ks) << 1) + ocq) << 11)) + (lane << 3);
      s16x8 af[2], bfr[4];
      #pragma unroll
      for (int mi = 0; mi < 2; mi++)
        af[mi] = *(const s16x8*)(wp8 + (((rowq << 1) + mi) << 9));
      const int gci = half * 4 + kb;
      #pragma unroll
      for (int ni = 0; ni < 4; ni++) {
        int r = (pxq << 6) + ni * 16 + nif;
        int w1 = r + dc;
        int slot = (gci + w1) & 7;
        bfr[ni] = *(const s16x8*)(sF + ((dr * 130 + w1) << 6) + slot * 8);
      }
      #pragma unroll
      for (int mi = 0; mi < 2; mi++)
        #pragma unroll
        for (int ni = 0; ni < 4; ni++)
          acc[mi][ni] = __builtin_amdgcn_mfma_f32_16x16x32_bf16(af[mi], bfr[ni], acc[mi][ni], 0, 0, 0);
    }
    __syncthreads();   // prior k's finalMFMA reads of colT complete (k=0: homT visible)

    // epilogue: tanh -> colT (slot-rotated), packed bf16 converts
    #pragma unroll
    for (int mi = 0; mi < 2; mi++) {
      #pragma unroll
      for (int ni = 0; ni < 4; ni++) {
        int px = (pxq << 6) + ni * 16 + nif;
        int c = (rowq << 5) + mi * 16 + (quad << 2);
        float4 b4 = *(const float4*)(Bc + 64 + (k << 6) + c);
        uint2 v2;
        v2.x = pkbf(fast_tanh(acc[mi][ni][0] + b4.x), fast_tanh(acc[mi][ni][1] + b4.y));
        v2.y = pkbf(fast_tanh(acc[mi][ni][2] + b4.z), fast_tanh(acc[mi][ni][3] + b4.w));
        int slot = ((c >> 3) + px) & 7;
        *(uint2*)(colT + (px << 6) + slot * 8 + (c & 7)) = v2;
      }
    }
    __syncthreads();   // colT visible to sampler

    // ---- sampler: 32 channels of pixel pxl, in-place update of colT ----
    {
      float ox = homT[pxl * 29 + k];
      float oy = homT[pxl * 29 + 9 + k];
      float mk = homT[pxl * 29 + 18 + k];
      float px_ = (float)(h + k / 3) + ox;
      float py_ = (float)(ww + k % 3) + oy;
      float fx = floorf(px_), fy = floorf(py_);
      float qltx = fminf(fmaxf(fx, 0.f), 129.f);
      float qlty = fminf(fmaxf(fy, 0.f), 129.f);
      float qrbx = fminf(fmaxf(fx + 1.f, 0.f), 129.f);
      float qrby = fminf(fmaxf(fy + 1.f, 0.f), 129.f);
      float sx = fminf(fmaxf(px_, 0.f), 129.f);
      float sy = fminf(fmaxf(py_, 0.f), 129.f);
      float ax = 1.f + qltx - sx, bx = 1.f - qrbx + sx;
      float ay = 1.f + qlty - sy, by = 1.f - qrby + sy;
      int iltx = (int)qltx, ilty = (int)qlty, irbx = (int)qrbx, irby = (int)qrby;
      bool vltx = (iltx >= 1) && (iltx <= 128);
      bool vlty = (ilty >= 1) && (ilty <= 128);
      bool vrbx = (irbx >= 1) && (irbx <= 128);
      bool vrby = (irby >= 1) && (irby <= 128);
      float wl[4];
      int   ofs[4];
      wl[0] = (vltx && vlty) ? ax * ay : 0.f;
      wl[1] = (vrbx && vrby) ? bx * by : 0.f;
      wl[2] = (vltx && vrby) ? ax * by : 0.f;
      wl[3] = (vrbx && vlty) ? bx * ay : 0.f;
      ofs[0] = (vltx && vlty) ? ((iltx - 1) << 7) + (ilty - 1) : 0;
      ofs[1] = (vrbx && vrby) ? ((irbx - 1) << 7) + (irby - 1) : 0;
      ofs[2] = (vltx && vrby) ? ((iltx - 1) << 7) + (irby - 1) : 0;
      ofs[3] = (vrbx && vlty) ? ((irbx - 1) << 7) + (ilty - 1) : 0;

      float pos[32];
      #pragma unroll
      for (int j = 0; j < 32; j++) pos[j] = 0.f;
      #pragma unroll
      for (int corner = 0; corner < 4; corner++) {
        const ushort* p = xb + ((size_t)ofs[corner] << 6) + c0;
        float wgt = wl[corner];
        ushort tmp[32];
        #pragma unroll
        for (int q2 = 0; q2 < 4; q2++)
          *(uint4*)(tmp + q2 * 8) = *(const uint4*)(p + q2 * 8);
        #pragma unroll
        for (int j = 0; j < 32; j++) pos[j] += wgt * bf2f(tmp[j]);
      }
      // read own col slots, update, write back (thread-exclusive -> no barrier)
      #pragma unroll
      for (int q2 = 0; q2 < 4; q2++) {
        int chunk = (chalf << 2) + q2;
        int slot = (chunk + pxl) & 7;
        ushort* cp = colT + (pxl << 6) + slot * 8;
        ushort ct[8];
        *(uint4*)ct = *(const uint4*)cp;
        float vv[8];
        #pragma unroll
        for (int j = 0; j < 8; j++)
          vv[j] = (bf2f(ct[j]) + pos[q2 * 8 + j]) * mk;
        uint4 ov;
        ov.x = pkbf(vv[0], vv[1]); ov.y = pkbf(vv[2], vv[3]);
        ov.z = pkbf(vv[4], vv[5]); ov.w = pkbf(vv[6], vv[7]);
        *(uint4*)cp = ov;
      }
    }
    __syncthreads();   // updated colT visible to MFMA

    // ---- final-GEMM MFMA: 2 ks-steps over this k-tile ----
    #pragma unroll
    for (int khalf = 0; khalf < 2; khalf++) {
      int ks2 = (k << 1) + khalf;
      s16x8 af[2], bfr[4];
      #pragma unroll
      for (int mi = 0; mi < 2; mi++)
        af[mi] = *(const s16x8*)(W2pk + ((((ks2 << 2) + (rowq << 1) + mi) << 6) + lane) * 8);
      const int g0 = (khalf << 2) + kb;
      #pragma unroll
      for (int ni = 0; ni < 4; ni++) {
        int r = (pxq << 6) + ni * 16 + nif;
        int slot = (g0 + r) & 7;
        bfr[ni] = *(const s16x8*)(colT + (r << 6) + slot * 8);
      }
      #pragma unroll
      for (int mi = 0; mi < 2; mi++)
        #pragma unroll
        for (int ni = 0; ni < 4; ni++)
          aco[mi][ni] = __builtin_amdgcn_mfma_f32_16x16x32_bf16(af[mi], bfr[ni], aco[mi][ni], 0, 0, 0);
    }
  }

  // ---- store out ----
  #pragma unroll
  for (int mi = 0; mi < 2; mi++) {
    #pragma unroll
    for (int ni = 0; ni < 4; ni++) {
      int hwp = hw0 + (pxq << 6) + ni * 16 + nif;
      #pragma unroll
      for (int r = 0; r < 4; r++) {
        int o = (rowq << 5) + mi * 16 + (quad << 2) + r;
        out[(((size_t)b * 64 + o) << 14) + hwp] = aco[mi][ni][r];
      }
    }
  }
}

extern "C" void kernel_launch(void* const* d_in, const int* in_sizes, int n_in,
                              void* d_out, int out_size, void* d_ws, size_t ws_size,
                              hipStream_t stream) {
  const float* x     = (const float*)d_in[0];
  const float* ref   = (const float*)d_in[1];
  const float* wcd   = (const float*)d_in[2];
  const float* bcd   = (const float*)d_in[3];
  const float* wp    = (const float*)d_in[4];
  const float* bp    = (const float*)d_in[5];
  const float* wm    = (const float*)d_in[6];
  const float* bm    = (const float*)d_in[7];
  const float* wc    = (const float*)d_in[8];
  const float* bc    = (const float*)d_in[9];
  const float* wconv = (const float*)d_in[10];
  float* out = (float*)d_out;

  char* w8 = (char*)d_ws;
  ushort* Wpk     = (ushort*)(w8 + 0);           //    737,280 B
  float*  Bc      = (float*)(w8 + 737280);       //      2,560 B
  ushort* W2pk    = (ushort*)(w8 + 739840);      //     73,728 B
  ushort* fusedt  = (ushort*)(w8 + 813568);      //  8,388,608 B (pixel-major)
  ushort* xtb     = (ushort*)(w8 + 9202176);     //  8,388,608 B -> total 17,590,784 B

  k_merge <<<1440, 256, 0, stream>>>(wp, bp, wm, bm, wc, bc, wconv, Wpk, Bc, W2pk);
  k_fused <<<1024, 256, 0, stream>>>(x, ref, wcd, bcd, fusedt);
  k_xt    <<<1024, 256, 0, stream>>>(x, xtb);
  k_all   <<<512, 256, 0, stream>>>(Wpk, fusedt, Bc, xtb, W2pk, out);
}

// Round 17
// 237.735 us; speedup vs baseline: 1.0200x; 1.0200x over previous
//
#include <hip/hip_runtime.h>
#include <hip/hip_bf16.h>
#include <math.h>

typedef short s16x8 __attribute__((ext_vector_type(8)));
typedef float f32x4 __attribute__((ext_vector_type(4)));

__device__ inline ushort f2bf(float f) {
  unsigned u = __float_as_uint(f);
  u = (u + 0x7FFF + ((u >> 16) & 1)) >> 16;
  return (ushort)u;
}
__device__ inline float bf2f(ushort u) {
  return __uint_as_float(((unsigned)u) << 16);
}
// packed f32x2 -> bf16x2 RNE (bit-identical to f2bf pair)
__device__ inline unsigned pkbf(float a, float b) {
  __hip_bfloat162 h = __float22bfloat162_rn(make_float2(a, b));
  return *(unsigned*)&h;
}
// fast activations: v_exp_f32 + v_rcp_f32; saturate correctly at +/-inf.
__device__ inline float fast_tanh(float v) {
  float e = __builtin_amdgcn_exp2f(v * 2.8853900817779268f);   // exp(2v)
  return 1.f - 2.f * __builtin_amdgcn_rcpf(e + 1.f);
}
__device__ inline float fast_sigmoid(float v) {
  float e = __builtin_amdgcn_exp2f(v * -1.4426950408889634f);  // exp(-v)
  return __builtin_amdgcn_rcpf(1.f + e);
}

// ---- PERMUTED head-row space (640 rows):
//   g in [0,18): off | [18,27): mod | [27,64): pad | [64,640): col j=g-64=k*64+c
//     source col channel cc = c*9+k.
// ---- K0: pack weights into MFMA-fragment order in permuted row space ------------------
// Wpk[og 5][ks 18][ocq 2][mi 4][lane 64][e 8]; W2pk[ks 18][mi 4][lane 64][e 8].
__global__ __launch_bounds__(256) void k_merge(
    const float* __restrict__ wp, const float* __restrict__ bp,
    const float* __restrict__ wm, const float* __restrict__ bm,
    const float* __restrict__ wc, const float* __restrict__ bc,
    const float* __restrict__ wconv,
    ushort* __restrict__ Wpk, float* __restrict__ Bc, ushort* __restrict__ W2pk) {
  int i = blockIdx.x * 256 + threadIdx.x;
  if (i < 368640) {
    int e = i & 7, lane = (i >> 3) & 63, mi = (i >> 9) & 3, ocq = (i >> 11) & 1;
    int hi = i >> 12;                 // 0..89
    int ks = hi % 18, og = hi / 18;
    int g = og * 128 + ocq * 64 + mi * 16 + (lane & 15);
    int ci = ((ks & 1) << 5) + ((lane >> 4) << 3) + e;
    int kk = ks >> 1;
    int col = ci * 9 + kk;
    float v = 0.f;
    if (g < 18)       v = wp[g * 576 + col];
    else if (g < 27)  v = wm[(g - 18) * 576 + col];
    else if (g >= 64) {
      int j = g - 64;
      int cc = (j & 63) * 9 + (j >> 6);
      v = wc[cc * 576 + col];
    }
    Wpk[i] = f2bf(v);
  }
  if (i < 36864) {
    int e = i & 7, lane = (i >> 3) & 63, mi = (i >> 9) & 3, ks = i >> 11;  // 0..17
    int o = mi * 16 + (lane & 15);
    int p = (ks << 5) + ((lane >> 4) << 3) + e;
    int kk2 = p >> 6, c = p & 63;
    W2pk[i] = f2bf(wconv[o * 576 + c * 9 + kk2]);
  }
  if (i < 640) {
    float bv = 0.f;
    if (i < 18)       bv = bp[i];
    else if (i < 27)  bv = bm[i - 18];
    else if (i >= 64) {
      int j = i - 64;
      bv = bc[(j & 63) * 9 + (j >> 6)];
    }
    Bc[i] = bv;
  }
}

// ---- K1: fused = 1x1 conv -> fusedt[pix][64] bf16. 4 thr/px x 16 oc, 16 waves/CU ------
__global__ __launch_bounds__(256) void k_fused(
    const float* __restrict__ x, const float* __restrict__ ref,
    const float* __restrict__ wcd, const float* __restrict__ bcd,
    ushort* __restrict__ fusedt) {
  __shared__ float sw[128 * 64];
  __shared__ float sb[64];
  for (int i = threadIdx.x; i < 128 * 64; i += 256) {
    int ci = i >> 6, o = i & 63;
    sw[i] = wcd[o * 128 + ci];
  }
  if (threadIdx.x < 64) sb[threadIdx.x] = bcd[threadIdx.x];
  __syncthreads();

  const int t = threadIdx.x;
  const int pxi = t & 63, oq = t >> 6;      // wave-uniform oq -> LDS broadcast
  const int pix = blockIdx.x * 64 + pxi;
  const int b = pix >> 14, hw = pix & 16383;
  const float* xb = x   + ((size_t)b * 64 << 14) + hw;
  const float* rb = ref + ((size_t)b * 64 << 14) + hw;

  float4 acc[4];
  #pragma unroll
  for (int q = 0; q < 4; q++)
    acc[q] = *(const float4*)&sb[oq * 16 + 4 * q];

  for (int ci = 0; ci < 64; ci++) {
    float v = xb[(size_t)ci << 14];
    const float4* wr = (const float4*)&sw[ci * 64 + oq * 16];
    #pragma unroll
    for (int q = 0; q < 4; q++) {
      float4 w4 = wr[q];
      acc[q].x += w4.x * v; acc[q].y += w4.y * v;
      acc[q].z += w4.z * v; acc[q].w += w4.w * v;
    }
  }
  for (int ci = 0; ci < 64; ci++) {
    float v = rb[(size_t)ci << 14];
    const float4* wr = (const float4*)&sw[(64 + ci) * 64 + oq * 16];
    #pragma unroll
    for (int q = 0; q < 4; q++) {
      float4 w4 = wr[q];
      acc[q].x += w4.x * v; acc[q].y += w4.y * v;
      acc[q].z += w4.z * v; acc[q].w += w4.w * v;
    }
  }
  uint4 o0, o1;
  o0.x = pkbf(acc[0].x, acc[0].y); o0.y = pkbf(acc[0].z, acc[0].w);
  o0.z = pkbf(acc[1].x, acc[1].y); o0.w = pkbf(acc[1].z, acc[1].w);
  o1.x = pkbf(acc[2].x, acc[2].y); o1.y = pkbf(acc[2].z, acc[2].w);
  o1.z = pkbf(acc[3].x, acc[3].y); o1.w = pkbf(acc[3].z, acc[3].w);
  ushort* fb = fusedt + ((size_t)pix << 6) + oq * 16;
  *(uint4*)fb       = o0;
  *(uint4*)(fb + 8) = o1;
}

// ---- K2: xtb[b][hw][c] bf16 pixel-major transpose of x -------------------------------
__global__ __launch_bounds__(256) void k_xt(
    const float* __restrict__ x, ushort* __restrict__ xtb) {
  __shared__ float sx[64][65];
  const int t = threadIdx.x;
  const int b = blockIdx.x >> 8, hw0 = (blockIdx.x & 255) << 6;
  for (int i = t; i < 4096; i += 256) {
    int c = i >> 6, hwi = i & 63;
    sx[c][hwi] = x[((size_t)(b * 64 + c) << 14) + hw0 + hwi];
  }
  __syncthreads();
  for (int i = t * 2; i < 4096; i += 512) {
    int hwi = i >> 6, c = i & 63;    // c even
    unsigned pk = pkbf(sx[c][hwi], sx[c + 1][hwi]);
    *(unsigned*)(xtb + (((size_t)b << 14) + hw0 + hwi) * 64 + c) = pk;
  }
}

// ---- K3: FULLY FUSED head-GEMM + sampler + final GEMM, 64-px tiles --------------------
// grid 1024 (half an image row per block); block 256 = 4 waves; 4 blocks/CU (LDS 40,448B).
// Wave roles: pxq = wv&1 (32 px), rowq = wv>>1 (32 GEMM rows / 32 out-oc).
__global__ __launch_bounds__(256) void k_all(
    const ushort* __restrict__ Wpk, const ushort* __restrict__ fusedt,
    const float* __restrict__ Bc, const ushort* __restrict__ xtb,
    const ushort* __restrict__ W2pk, float* __restrict__ out) {
  __shared__ __align__(16) ushort sF[3 * 66 * 64];    // 25,344 B
  __shared__ __align__(16) ushort colT[64 * 64];      //  8,192 B
  __shared__ float homT[64 * 27];                     //  6,912 B
  const int t = threadIdx.x;
  const int lane = t & 63, wv = t >> 6;
  const int rowid = blockIdx.x;           // b*256 + h*2 + half
  const int b = rowid >> 8;
  const int rem = rowid & 255;
  const int h = rem >> 1, hf = rem & 1;
  const int w0 = hf << 6;
  const int hw0 = (h << 7) + w0;

  // stage fused rows h-1..h+1, w1 in [0,66) covering gw in [w0-1, w0+64]
  for (int idx = t; idx < 1584; idx += 256) {   // 198 pixels x 8 ci-chunks
    int p = idx >> 3, j = idx & 7;
    int row = p / 66, w1 = p - row * 66;
    int gh = h + row - 1, gw = w0 + w1 - 1;
    uint4 v = make_uint4(0u, 0u, 0u, 0u);
    if (gh >= 0 && gh < 128 && (unsigned)gw < 128u)
      v = *(const uint4*)(fusedt + ((size_t)((b << 14) + (gh << 7) + gw) << 6) + j * 8);
    int slot = (j + w1) & 7;
    *(uint4*)(sF + (p << 6) + slot * 8) = v;
  }
  __syncthreads();

  const int pxq = wv & 1, rowq = wv >> 1;
  const int nif = lane & 15, kb = lane >> 4, quad = lane >> 4;

  // ---- off/mod GEMM: permuted rows 0..31 (rowq==0 waves only) ----
  if (rowq == 0) {
    f32x4 acc[2][2];
    #pragma unroll
    for (int mi = 0; mi < 2; mi++)
      #pragma unroll
      for (int ni = 0; ni < 2; ni++) acc[mi][ni] = (f32x4){0.f, 0.f, 0.f, 0.f};
    #pragma unroll 2
    for (int ks = 0; ks < 18; ks++) {
      const int kk = ks >> 1, half = ks & 1;
      const int dr = kk / 3, dc = kk - dr * 3;
      const ushort* wp8 = Wpk + ((size_t)(ks << 12)) + (lane << 3);  // og=0, ocq=0
      s16x8 af[2], bfr[2];
      #pragma unroll
      for (int mi = 0; mi < 2; mi++)
        af[mi] = *(const s16x8*)(wp8 + (mi << 9));
      const int gci = half * 4 + kb;
      #pragma unroll
      for (int ni = 0; ni < 2; ni++) {
        int r = (pxq << 5) + ni * 16 + nif;
        int w1 = r + dc;
        int slot = (gci + w1) & 7;
        bfr[ni] = *(const s16x8*)(sF + ((dr * 66 + w1) << 6) + slot * 8);
      }
      #pragma unroll
      for (int mi = 0; mi < 2; mi++)
        #pragma unroll
        for (int ni = 0; ni < 2; ni++)
          acc[mi][ni] = __builtin_amdgcn_mfma_f32_16x16x32_bf16(af[mi], bfr[ni], acc[mi][ni], 0, 0, 0);
    }
    #pragma unroll
    for (int mi = 0; mi < 2; mi++) {
      #pragma unroll
      for (int ni = 0; ni < 2; ni++) {
        int px = (pxq << 5) + ni * 16 + nif;
        #pragma unroll
        for (int r = 0; r < 4; r++) {
          int g = mi * 16 + (quad << 2) + r;
          float v = acc[mi][ni][r] + Bc[g];
          if (g < 18)       homT[px * 27 + g] = v;
          else if (g < 27)  homT[px * 27 + g] = fast_sigmoid(v);
        }
      }
    }
  }

  // sampler per-pixel identity: 4 thr/px x 16 ch
  const int cq = t >> 6, pxl = t & 63, c0 = cq << 4;
  const int ww = w0 + pxl;
  const ushort* xb = xtb + ((size_t)b << 20);

  f32x4 aco[2][2];
  #pragma unroll
  for (int mi = 0; mi < 2; mi++)
    #pragma unroll
    for (int ni = 0; ni < 2; ni++) aco[mi][ni] = (f32x4){0.f, 0.f, 0.f, 0.f};

  #pragma unroll 1
  for (int k = 0; k < 9; k++) {
    // ---- col GEMM for this k: permuted rows 64+k*64 .. 128+k*64 ----
    const int q = 1 + k, og = q >> 1, ocq = q & 1;
    f32x4 acc[2][2];
    #pragma unroll
    for (int mi = 0; mi < 2; mi++)
      #pragma unroll
      for (int ni = 0; ni < 2; ni++) acc[mi][ni] = (f32x4){0.f, 0.f, 0.f, 0.f};
    #pragma unroll 2
    for (int ks = 0; ks < 18; ks++) {
      const int kk = ks >> 1, half = ks & 1;
      const int dr = kk / 3, dc = kk - dr * 3;
      const ushort* wp8 = Wpk + ((size_t)((((og * 18 + ks) << 1) + ocq) << 11)) + (lane << 3);
      s16x8 af[2], bfr[2];
      #pragma unroll
      for (int mi = 0; mi < 2; mi++)
        af[mi] = *(const s16x8*)(wp8 + (((rowq << 1) + mi) << 9));
      const int gci = half * 4 + kb;
      #pragma unroll
      for (int ni = 0; ni < 2; ni++) {
        int r = (pxq << 5) + ni * 16 + nif;
        int w1 = r + dc;
        int slot = (gci + w1) & 7;
        bfr[ni] = *(const s16x8*)(sF + ((dr * 66 + w1) << 6) + slot * 8);
      }
      #pragma unroll
      for (int mi = 0; mi < 2; mi++)
        #pragma unroll
        for (int ni = 0; ni < 2; ni++)
          acc[mi][ni] = __builtin_amdgcn_mfma_f32_16x16x32_bf16(af[mi], bfr[ni], acc[mi][ni], 0, 0, 0);
    }
    __syncthreads();   // prior k's finalMFMA reads of colT complete (k=0: homT visible)

    // epilogue: tanh -> colT (slot-rotated)
    #pragma unroll
    for (int mi = 0; mi < 2; mi++) {
      #pragma unroll
      for (int ni = 0; ni < 2; ni++) {
        int px = (pxq << 5) + ni * 16 + nif;
        int c = (rowq << 5) + mi * 16 + (quad << 2);
        float4 b4 = *(const float4*)(Bc + 64 + (k << 6) + c);
        ushort v4[4];
        v4[0] = f2bf(fast_tanh(acc[mi][ni][0] + b4.x));
        v4[1] = f2bf(fast_tanh(acc[mi][ni][1] + b4.y));
        v4[2] = f2bf(fast_tanh(acc[mi][ni][2] + b4.z));
        v4[3] = f2bf(fast_tanh(acc[mi][ni][3] + b4.w));
        int slot = ((c >> 3) + px) & 7;
        *(uint2*)(colT + (px << 6) + slot * 8 + (c & 7)) = *(uint2*)v4;
      }
    }
    __syncthreads();   // colT visible to sampler

    // ---- sampler: 16 channels of pixel pxl, in-place update of colT ----
    {
      float ox = homT[pxl * 27 + k];
      float oy = homT[pxl * 27 + 9 + k];
      float mk = homT[pxl * 27 + 18 + k];
      float px_ = (float)(h + k / 3) + ox;
      float py_ = (float)(ww + k % 3) + oy;
      float fx = floorf(px_), fy = floorf(py_);
      float qltx = fminf(fmaxf(fx, 0.f), 129.f);
      float qlty = fminf(fmaxf(fy, 0.f), 129.f);
      float qrbx = fminf(fmaxf(fx + 1.f, 0.f), 129.f);
      float qrby = fminf(fmaxf(fy + 1.f, 0.f), 129.f);
      float sx = fminf(fmaxf(px_, 0.f), 129.f);
      float sy = fminf(fmaxf(py_, 0.f), 129.f);
      float ax = 1.f + qltx - sx, bx = 1.f - qrbx + sx;
      float ay = 1.f + qlty - sy, by = 1.f - qrby + sy;
      int iltx = (int)qltx, ilty = (int)qlty, irbx = (int)qrbx, irby = (int)qrby;
      bool vltx = (iltx >= 1) && (iltx <= 128);
      bool vlty = (ilty >= 1) && (ilty <= 128);
      bool vrbx = (irbx >= 1) && (irbx <= 128);
      bool vrby = (irby >= 1) && (irby <= 128);
      float wl[4];
      int   ofs[4];
      wl[0] = (vltx && vlty) ? ax * ay : 0.f;
      wl[1] = (vrbx && vrby) ? bx * by : 0.f;
      wl[2] = (vltx && vrby) ? ax * by : 0.f;
      wl[3] = (vrbx && vlty) ? bx * ay : 0.f;
      ofs[0] = (vltx && vlty) ? ((iltx - 1) << 7) + (ilty - 1) : 0;
      ofs[1] = (vrbx && vrby) ? ((irbx - 1) << 7) + (irby - 1) : 0;
      ofs[2] = (vltx && vrby) ? ((iltx - 1) << 7) + (irby - 1) : 0;
      ofs[3] = (vrbx && vlty) ? ((irbx - 1) << 7) + (ilty - 1) : 0;

      float pos[16];
      #pragma unroll
      for (int j = 0; j < 16; j++) pos[j] = 0.f;
      #pragma unroll
      for (int corner = 0; corner < 4; corner++) {
        const ushort* p = xb + ((size_t)ofs[corner] << 6) + c0;
        float wgt = wl[corner];
        ushort tmp[16];
        *(uint4*)(tmp)     = *(const uint4*)(p);
        *(uint4*)(tmp + 8) = *(const uint4*)(p + 8);
        #pragma unroll
        for (int j = 0; j < 16; j++) pos[j] += wgt * bf2f(tmp[j]);
      }
      // read own col slots, update, write back (thread-exclusive -> no barrier)
      #pragma unroll
      for (int q2 = 0; q2 < 2; q2++) {
        int chunk = (cq << 1) + q2;
        int slot = (chunk + pxl) & 7;
        ushort* cp = colT + (pxl << 6) + slot * 8;
        ushort ct[8];
        *(uint4*)ct = *(const uint4*)cp;
        #pragma unroll
        for (int j = 0; j < 8; j++)
          ct[j] = f2bf((bf2f(ct[j]) + pos[q2 * 8 + j]) * mk);
        *(uint4*)cp = *(uint4*)ct;
      }
    }
    __syncthreads();   // updated colT visible to MFMA

    // ---- final-GEMM MFMA: 2 ks-steps over this k-tile ----
    #pragma unroll
    for (int khalf = 0; khalf < 2; khalf++) {
      int ks2 = (k << 1) + khalf;
      s16x8 af[2], bfr[2];
      #pragma unroll
      for (int mi = 0; mi < 2; mi++)
        af[mi] = *(const s16x8*)(W2pk + ((((ks2 << 2) + (rowq << 1) + mi) << 6) + lane) * 8);
      const int g0 = (khalf << 2) + kb;
      #pragma unroll
      for (int ni = 0; ni < 2; ni++) {
        int r = (pxq << 5) + ni * 16 + nif;
        int slot = (g0 + r) & 7;
        bfr[ni] = *(const s16x8*)(colT + (r << 6) + slot * 8);
      }
      #pragma unroll
      for (int mi = 0; mi < 2; mi++)
        #pragma unroll
        for (int ni = 0; ni < 2; ni++)
          aco[mi][ni] = __builtin_amdgcn_mfma_f32_16x16x32_bf16(af[mi], bfr[ni], aco[mi][ni], 0, 0, 0);
    }
  }

  // ---- store out ----
  #pragma unroll
  for (int mi = 0; mi < 2; mi++) {
    #pragma unroll
    for (int ni = 0; ni < 2; ni++) {
      int hwp = hw0 + (pxq << 5) + ni * 16 + nif;
      #pragma unroll
      for (int r = 0; r < 4; r++) {
        int o = (rowq << 5) + mi * 16 + (quad << 2) + r;
        out[(((size_t)b * 64 + o) << 14) + hwp] = aco[mi][ni][r];
      }
    }
  }
}

extern "C" void kernel_launch(void* const* d_in, const int* in_sizes, int n_in,
                              void* d_out, int out_size, void* d_ws, size_t ws_size,
                              hipStream_t stream) {
  const float* x     = (const float*)d_in[0];
  const float* ref   = (const float*)d_in[1];
  const float* wcd   = (const float*)d_in[2];
  const float* bcd   = (const float*)d_in[3];
  const float* wp    = (const float*)d_in[4];
  const float* bp    = (const float*)d_in[5];
  const float* wm    = (const float*)d_in[6];
  const float* bm    = (const float*)d_in[7];
  const float* wc    = (const float*)d_in[8];
  const float* bc    = (const float*)d_in[9];
  const float* wconv = (const float*)d_in[10];
  float* out = (float*)d_out;

  char* w8 = (char*)d_ws;
  ushort* Wpk     = (ushort*)(w8 + 0);           //    737,280 B
  float*  Bc      = (float*)(w8 + 737280);       //      2,560 B
  ushort* W2pk    = (ushort*)(w8 + 739840);      //     73,728 B
  ushort* fusedt  = (ushort*)(w8 + 813568);      //  8,388,608 B (pixel-major)
  ushort* xtb     = (ushort*)(w8 + 9202176);     //  8,388,608 B -> total 17,590,784 B

  k_merge <<<1440, 256, 0, stream>>>(wp, bp, wm, bm, wc, bc, wconv, Wpk, Bc, W2pk);
  k_fused <<<1024, 256, 0, stream>>>(x, ref, wcd, bcd, fusedt);
  k_xt    <<<1024, 256, 0, stream>>>(x, xtb);
  k_all   <<<1024, 256, 0, stream>>>(Wpk, fusedt, Bc, xtb, W2pk, out);
}